// Round 9
// baseline (524.081 us; speedup 1.0000x reference)
//
#include <hip/hip_runtime.h>
#include <hip/hip_bf16.h>
#include <stdint.h>

// Problem constants
#define B_ROWS 131072
#define DD 256
#define KEXP 8
#define HH 128
#define BM 128        // rows per workgroup (4 waves x 32 rows, 32x32 MFMA)
#define NW 4          // waves per workgroup

typedef float  f32x4   __attribute__((ext_vector_type(4)));
typedef float  f32x16  __attribute__((ext_vector_type(16)));
typedef short  bf16x8  __attribute__((ext_vector_type(8)));

__device__ __forceinline__ unsigned short f2bf(float f) {
    uint32_t u = __builtin_bit_cast(uint32_t, f);
    u += 0x7fffu + ((u >> 16) & 1u);   // RTNE
    return (unsigned short)(u >> 16);
}

// exact-erf GELU via Abramowitz-Stegun 7.1.26 (|erf err| <= 1.5e-7)
__device__ __forceinline__ float gelu_erf(float x) {
    float s = x * 0.70710678118654752f;
    float a = fabsf(s);
    float t = __builtin_amdgcn_rcpf(fmaf(0.3275911f, a, 1.0f));
    float p = fmaf(t, 1.061405429f, -1.453152027f);
    p = fmaf(t, p, 1.421413741f);
    p = fmaf(t, p, -0.284496736f);
    p = fmaf(t, p, 0.254829592f);
    float e = __expf(-a * a);
    float Q = p * t * e;                        // = 1 - erf(a)
    float sel = (s >= 0.f) ? (2.0f - Q) : Q;    // 1 + erf(s)
    return 0.5f * x * sel;
}

__device__ __forceinline__ bf16x8 gelu_pack8(float v0, float v1, float v2, float v3,
                                             float v4, float v5, float v6, float v7) {
    bf16x8 r;
    r[0] = f2bf(gelu_erf(v0)); r[1] = f2bf(gelu_erf(v1));
    r[2] = f2bf(gelu_erf(v2)); r[3] = f2bf(gelu_erf(v3));
    r[4] = f2bf(gelu_erf(v4)); r[5] = f2bf(gelu_erf(v5));
    r[6] = f2bf(gelu_erf(v6)); r[7] = f2bf(gelu_erf(v7));
    return r;
}

// Preconvert for 32x32x16 MFMA consumption:
//   W1 -> bf16 [k][h-row:128][32 slots][8], slot sc holds d-chunk kc = sc ^ (h&7).
//   W2 -> bf16 [k][g2-row:128][16 slots][8], slot sc holds h-chunk kc = sc ^ (g2&7),
//         k-axis permuted by pi = SWAP BITS 2<->3, derived from the 32x32 C/D layout
//         (row = (reg&3) + 8*(reg>>2) + 4*(lane>>5), m74/m101) vs the B-operand slot
//         structure (k = 16*t2 + 8*(lane>>5) + j): packing pa[2q][j]=acc[j],
//         pa[2q+1][j]=acc[8+j] then makes h(pa slot) == pi(k slot) exactly.
__global__ void convert_weights(const float* __restrict__ W1, const float* __restrict__ W2,
                                uint16_t* __restrict__ w1o, uint16_t* __restrict__ w2o) {
    int idx = blockIdx.x * blockDim.x + threadIdx.x;
    const int total1 = KEXP * HH * DD;           // 262144
    if (idx < total1) {
        int k   = idx >> 15;
        int rem = idx & 32767;
        int h   = rem >> 8;
        int r2  = rem & 255;
        int sc  = r2 >> 3;                       // 0..31
        int j   = r2 & 7;
        int kc  = sc ^ (h & 7);
        int d   = kc * 8 + j;
        w1o[idx] = f2bf(W1[(k * DD + d) * HH + h]);
        return;
    }
    int idx2 = idx - total1;
    const int total2 = KEXP * HH * HH;           // 131072
    if (idx2 < total2) {
        int k   = idx2 >> 14;
        int rem = idx2 & 16383;
        int gr  = rem >> 7;
        int r2  = rem & 127;
        int sc  = r2 >> 3;                       // 0..15
        int j   = r2 & 7;
        int kk  = (sc ^ (gr & 7)) * 8 + j;       // logical k position
        int h   = (kk & ~12) | ((kk & 4) << 1) | ((kk & 8) >> 1);   // pi: swap bits 2,3
        w2o[idx2] = f2bf(W2[(k * HH + h) * HH + gr]);
    }
}

// stage 16KB with 256 threads: 4 waves x 4 iters x (64 lanes x 16B).
// LDS dest is wave-uniform base + lane*16 (HW rule); source layout is linear-matching.
__device__ __forceinline__ void stage16k(const uint16_t* __restrict__ src, uint16_t* dst,
                                         int wave, int lane) {
    const char* s = (const char*)src + wave * 1024 + lane * 16;
    char* d = (char*)dst + wave * 1024;
    #pragma unroll
    for (int i = 0; i < 4; ++i)
        __builtin_amdgcn_global_load_lds(
            (const __attribute__((address_space(1))) void*)(s + i * 4096),
            (__attribute__((address_space(3))) void*)(d + i * 4096), 16, 0, 0);
}

__global__ __launch_bounds__(256, 3)
void moe_kernel(const float* __restrict__ z, const float* __restrict__ probs,
                const float* __restrict__ b1, const float* __restrict__ b2,
                const float* __restrict__ W3, const float* __restrict__ b3,
                const uint16_t* __restrict__ w1b, const uint16_t* __restrict__ w2b,
                float* __restrict__ out) {
    __shared__ __align__(16) uint16_t wbuf[2][8192];      // 2 x 16 KB ping-pong
    __shared__ __align__(16) float preds_lds[BM * KEXP];  // 4 KB

    const int tid  = threadIdx.x;
    const int wave = tid >> 6;
    const int lane = tid & 63;
    const int r31  = lane & 31;    // A row (h/g2) and C/D col (batch row m)
    const int lh   = lane >> 5;    // lane half
    const int wg   = blockIdx.x;
    const long rowbase = (long)wg * BM;

    // z fragments: lane holds z[m = wave*32 + r31][d = 16t + 8*lh + j], t = 0..15
    bf16x8 zf[16];
    {
        const float* zr = z + (rowbase + wave * 32 + r31) * DD + lh * 8;
        #pragma unroll
        for (int t = 0; t < 16; ++t) {
            float4 x0 = *(const float4*)(zr + t * 16);
            float4 x1 = *(const float4*)(zr + t * 16 + 4);
            bf16x8 f;
            f[0] = f2bf(x0.x); f[1] = f2bf(x0.y); f[2] = f2bf(x0.z); f[3] = f2bf(x0.w);
            f[4] = f2bf(x1.x); f[5] = f2bf(x1.y); f[6] = f2bf(x1.z); f[7] = f2bf(x1.w);
            zf[t] = f;
        }
    }

    // prologue: stage expert 0, W1 quarter 0
    stage16k(w1b, wbuf[0], wave, lane);
    __syncthreads();

    int cur = 0;
    const int swz = lane & 7;      // XOR key: (row&7) for both W1 and W2 reads

    for (int ke = 0; ke < KEXP; ++ke) {
        bf16x8 pa[8];
        const uint16_t* w1e = w1b + ke * (HH * DD);
        const uint16_t* w2e = w2b + ke * (HH * HH);
        const float* bb1 = b1 + ke * HH;

        // ---- phases 0-3: layer-1 quarter q (32 h-rows, 16KB); stage next ----
        #pragma unroll
        for (int q = 0; q < 4; ++q) {
            if (q < 3) stage16k(w1e + (q + 1) * 8192, wbuf[cur ^ 1], wave, lane);
            else       stage16k(w2e,                  wbuf[cur ^ 1], wave, lane);

            // bias init: acc[reg] = b1[32q + (reg&3) + 8*(reg>>2) + 4*lh]
            f32x16 acc;
            {
                const float* bq = bb1 + 32 * q + 4 * lh;
                #pragma unroll
                for (int qd = 0; qd < 4; ++qd) {
                    f32x4 bv = *(const f32x4*)(bq + 8 * qd);
                    acc[4 * qd + 0] = bv[0]; acc[4 * qd + 1] = bv[1];
                    acc[4 * qd + 2] = bv[2]; acc[4 * qd + 3] = bv[3];
                }
            }
            const uint16_t* wrow = wbuf[cur] + r31 * 256;
            #pragma unroll
            for (int t = 0; t < 16; ++t) {
                int slot = (2 * t + lh) ^ swz;
                bf16x8 af = *(const bf16x8*)(wrow + slot * 8);
                acc = __builtin_amdgcn_mfma_f32_32x32x16_bf16(af, zf[t], acc, 0, 0, 0);
            }
            pa[2 * q]     = gelu_pack8(acc[0], acc[1], acc[2], acc[3], acc[4], acc[5], acc[6], acc[7]);
            pa[2 * q + 1] = gelu_pack8(acc[8], acc[9], acc[10], acc[11], acc[12], acc[13], acc[14], acc[15]);
            __syncthreads(); cur ^= 1;
        }

        float part = 0.f;

        // ---- phase E: layer-2 g2 rows 0-63 (2 MFMA blocks); stage W2 half 1 ----
        {
            stage16k(w2e + 8192, wbuf[cur ^ 1], wave, lane);
            f32x16 c0, c1;
            {
                const float* bq = b2 + ke * HH + 4 * lh;
                #pragma unroll
                for (int qd = 0; qd < 4; ++qd) {
                    f32x4 v0 = *(const f32x4*)(bq + 8 * qd);
                    f32x4 v1 = *(const f32x4*)(bq + 32 + 8 * qd);
                    c0[4 * qd + 0] = v0[0]; c0[4 * qd + 1] = v0[1]; c0[4 * qd + 2] = v0[2]; c0[4 * qd + 3] = v0[3];
                    c1[4 * qd + 0] = v1[0]; c1[4 * qd + 1] = v1[1]; c1[4 * qd + 2] = v1[2]; c1[4 * qd + 3] = v1[3];
                }
            }
            const uint16_t* wr0 = wbuf[cur] + r31 * 128;
            const uint16_t* wr1 = wbuf[cur] + (32 + r31) * 128;
            #pragma unroll
            for (int t2 = 0; t2 < 8; ++t2) {
                int slot = (2 * t2 + lh) ^ swz;
                c0 = __builtin_amdgcn_mfma_f32_32x32x16_bf16(*(const bf16x8*)(wr0 + slot * 8), pa[t2], c0, 0, 0, 0);
                c1 = __builtin_amdgcn_mfma_f32_32x32x16_bf16(*(const bf16x8*)(wr1 + slot * 8), pa[t2], c1, 0, 0, 0);
            }
            const float* w3p = W3 + ke * HH + 4 * lh;
            #pragma unroll
            for (int qd = 0; qd < 4; ++qd) {
                f32x4 w0 = *(const f32x4*)(w3p + 8 * qd);
                f32x4 w1v = *(const f32x4*)(w3p + 32 + 8 * qd);
                part = fmaf(gelu_erf(c0[4 * qd + 0]), w0[0], part);
                part = fmaf(gelu_erf(c0[4 * qd + 1]), w0[1], part);
                part = fmaf(gelu_erf(c0[4 * qd + 2]), w0[2], part);
                part = fmaf(gelu_erf(c0[4 * qd + 3]), w0[3], part);
                part = fmaf(gelu_erf(c1[4 * qd + 0]), w1v[0], part);
                part = fmaf(gelu_erf(c1[4 * qd + 1]), w1v[1], part);
                part = fmaf(gelu_erf(c1[4 * qd + 2]), w1v[2], part);
                part = fmaf(gelu_erf(c1[4 * qd + 3]), w1v[3], part);
            }
            __syncthreads(); cur ^= 1;
        }

        // ---- phase F: layer-2 g2 rows 64-127; stage next expert's W1 q0; reduce ----
        {
            if (ke + 1 < KEXP) stage16k(w1b + (ke + 1) * (HH * DD), wbuf[cur ^ 1], wave, lane);
            f32x16 c0, c1;
            {
                const float* bq = b2 + ke * HH + 64 + 4 * lh;
                #pragma unroll
                for (int qd = 0; qd < 4; ++qd) {
                    f32x4 v0 = *(const f32x4*)(bq + 8 * qd);
                    f32x4 v1 = *(const f32x4*)(bq + 32 + 8 * qd);
                    c0[4 * qd + 0] = v0[0]; c0[4 * qd + 1] = v0[1]; c0[4 * qd + 2] = v0[2]; c0[4 * qd + 3] = v0[3];
                    c1[4 * qd + 0] = v1[0]; c1[4 * qd + 1] = v1[1]; c1[4 * qd + 2] = v1[2]; c1[4 * qd + 3] = v1[3];
                }
            }
            const uint16_t* wr0 = wbuf[cur] + r31 * 128;
            const uint16_t* wr1 = wbuf[cur] + (32 + r31) * 128;
            #pragma unroll
            for (int t2 = 0; t2 < 8; ++t2) {
                int slot = (2 * t2 + lh) ^ swz;
                c0 = __builtin_amdgcn_mfma_f32_32x32x16_bf16(*(const bf16x8*)(wr0 + slot * 8), pa[t2], c0, 0, 0, 0);
                c1 = __builtin_amdgcn_mfma_f32_32x32x16_bf16(*(const bf16x8*)(wr1 + slot * 8), pa[t2], c1, 0, 0, 0);
            }
            const float* w3p = W3 + ke * HH + 64 + 4 * lh;
            #pragma unroll
            for (int qd = 0; qd < 4; ++qd) {
                f32x4 w0 = *(const f32x4*)(w3p + 8 * qd);
                f32x4 w1v = *(const f32x4*)(w3p + 32 + 8 * qd);
                part = fmaf(gelu_erf(c0[4 * qd + 0]), w0[0], part);
                part = fmaf(gelu_erf(c0[4 * qd + 1]), w0[1], part);
                part = fmaf(gelu_erf(c0[4 * qd + 2]), w0[2], part);
                part = fmaf(gelu_erf(c0[4 * qd + 3]), w0[3], part);
                part = fmaf(gelu_erf(c1[4 * qd + 0]), w1v[0], part);
                part = fmaf(gelu_erf(c1[4 * qd + 1]), w1v[1], part);
                part = fmaf(gelu_erf(c1[4 * qd + 2]), w1v[2], part);
                part = fmaf(gelu_erf(c1[4 * qd + 3]), w1v[3], part);
            }
            part += __shfl_xor(part, 32);   // lanes l and l+32 share batch row m = l&31
            if (lane < 32)
                preds_lds[(wave * 32 + lane) * KEXP + ke] = part + b3[ke];
            __syncthreads(); cur ^= 1;
        }
    }

    // expert_preds: coalesced 1024 f32 per WG
    {
        float4 v = *(const float4*)(preds_lds + tid * 4);
        *(float4*)(out + B_ROWS + rowbase * KEXP + tid * 4) = v;
    }
    // blended: 128 f32 per WG (probs straight from global, coalesced)
    if (tid < BM) {
        const float* pr = probs + (rowbase + tid) * KEXP;
        float4 p0 = *(const float4*)(pr);
        float4 p1 = *(const float4*)(pr + 4);
        const float* pd = preds_lds + tid * KEXP;
        float s = 0.f;
        s = fmaf(p0.x, pd[0], s); s = fmaf(p0.y, pd[1], s);
        s = fmaf(p0.z, pd[2], s); s = fmaf(p0.w, pd[3], s);
        s = fmaf(p1.x, pd[4], s); s = fmaf(p1.y, pd[5], s);
        s = fmaf(p1.z, pd[6], s); s = fmaf(p1.w, pd[7], s);
        out[rowbase + tid] = s;
    }
}

extern "C" void kernel_launch(void* const* d_in, const int* in_sizes, int n_in,
                              void* d_out, int out_size, void* d_ws, size_t ws_size,
                              hipStream_t stream) {
    const float* z     = (const float*)d_in[0];
    const float* probs = (const float*)d_in[1];
    const float* W1    = (const float*)d_in[2];
    const float* b1    = (const float*)d_in[3];
    const float* W2    = (const float*)d_in[4];
    const float* b2    = (const float*)d_in[5];
    const float* W3    = (const float*)d_in[6];
    const float* b3    = (const float*)d_in[7];
    float* out = (float*)d_out;

    uint16_t* w1b = (uint16_t*)d_ws;                       // 8*128*256 bf16 = 512 KB
    uint16_t* w2b = w1b + (size_t)KEXP * HH * DD;          // 8*128*128 bf16 = 256 KB

    const int totalw = KEXP * HH * DD + KEXP * HH * HH;    // 393216
    convert_weights<<<(totalw + 255) / 256, 256, 0, stream>>>(W1, W2, w1b, w2b);
    moe_kernel<<<B_ROWS / BM, 256, 0, stream>>>(z, probs, b1, b2, W3, b3, w1b, w2b, out);
}

// Round 10
// 241.579 us; speedup vs baseline: 2.1694x; 2.1694x over previous
//
#include <hip/hip_runtime.h>
#include <hip/hip_bf16.h>
#include <stdint.h>

// Problem constants
#define B_ROWS 131072
#define DD 256
#define KEXP 8
#define HH 128
#define BM 64         // rows per workgroup (2 waves x 32 rows, 32x32 MFMA)
#define NW 2          // waves per workgroup

typedef float  f32x4   __attribute__((ext_vector_type(4)));
typedef float  f32x16  __attribute__((ext_vector_type(16)));
typedef short  bf16x8  __attribute__((ext_vector_type(8)));

__device__ __forceinline__ unsigned short f2bf(float f) {
    uint32_t u = __builtin_bit_cast(uint32_t, f);
    u += 0x7fffu + ((u >> 16) & 1u);   // RTNE
    return (unsigned short)(u >> 16);
}

// exact-erf GELU via Abramowitz-Stegun 7.1.26 (|erf err| <= 1.5e-7)
__device__ __forceinline__ float gelu_erf(float x) {
    float s = x * 0.70710678118654752f;
    float a = fabsf(s);
    float t = __builtin_amdgcn_rcpf(fmaf(0.3275911f, a, 1.0f));
    float p = fmaf(t, 1.061405429f, -1.453152027f);
    p = fmaf(t, p, 1.421413741f);
    p = fmaf(t, p, -0.284496736f);
    p = fmaf(t, p, 0.254829592f);
    float e = __expf(-a * a);
    float Q = p * t * e;                        // = 1 - erf(a)
    float sel = (s >= 0.f) ? (2.0f - Q) : Q;    // 1 + erf(s)
    return 0.5f * x * sel;
}

__device__ __forceinline__ bf16x8 gelu_pack8(float v0, float v1, float v2, float v3,
                                             float v4, float v5, float v6, float v7) {
    bf16x8 r;
    r[0] = f2bf(gelu_erf(v0)); r[1] = f2bf(gelu_erf(v1));
    r[2] = f2bf(gelu_erf(v2)); r[3] = f2bf(gelu_erf(v3));
    r[4] = f2bf(gelu_erf(v4)); r[5] = f2bf(gelu_erf(v5));
    r[6] = f2bf(gelu_erf(v6)); r[7] = f2bf(gelu_erf(v7));
    return r;
}

// Preconvert for 32x32x16 MFMA consumption (verified by round-9 pass):
//   W1 -> bf16 [k][h-row:128][32 slots][8], slot sc holds d-chunk kc = sc ^ (h&7).
//   W2 -> bf16 [k][g2-row:128][16 slots][8], slot sc holds h-chunk kc = sc ^ (g2&7),
//         k-axis permuted by pi = SWAP BITS 2<->3 (32x32 C/D row = (reg&3)+8*(reg>>2)+4*lh
//         vs B slot k = 16*t2+8*lh+j; packing pa[2q][j]=acc[j], pa[2q+1][j]=acc[8+j]).
__global__ void convert_weights(const float* __restrict__ W1, const float* __restrict__ W2,
                                uint16_t* __restrict__ w1o, uint16_t* __restrict__ w2o) {
    int idx = blockIdx.x * blockDim.x + threadIdx.x;
    const int total1 = KEXP * HH * DD;           // 262144
    if (idx < total1) {
        int k   = idx >> 15;
        int rem = idx & 32767;
        int h   = rem >> 8;
        int r2  = rem & 255;
        int sc  = r2 >> 3;                       // 0..31
        int j   = r2 & 7;
        int kc  = sc ^ (h & 7);
        int d   = kc * 8 + j;
        w1o[idx] = f2bf(W1[(k * DD + d) * HH + h]);
        return;
    }
    int idx2 = idx - total1;
    const int total2 = KEXP * HH * HH;           // 131072
    if (idx2 < total2) {
        int k   = idx2 >> 14;
        int rem = idx2 & 16383;
        int gr  = rem >> 7;
        int r2  = rem & 127;
        int sc  = r2 >> 3;                       // 0..15
        int j   = r2 & 7;
        int kk  = (sc ^ (gr & 7)) * 8 + j;       // logical k position
        int h   = (kk & ~12) | ((kk & 4) << 1) | ((kk & 8) >> 1);   // pi: swap bits 2,3
        w2o[idx2] = f2bf(W2[(k * HH + h) * HH + gr]);
    }
}

// stage 16KB with 128 threads: 2 waves x 8 iters x (64 lanes x 16B).
// LDS dest is wave-uniform base + lane*16 (HW rule).
__device__ __forceinline__ void stage16k(const uint16_t* __restrict__ src, uint16_t* dst,
                                         int wave, int lane) {
    const char* s = (const char*)src + wave * 1024 + lane * 16;
    char* d = (char*)dst + wave * 1024;
    #pragma unroll
    for (int i = 0; i < 8; ++i)
        __builtin_amdgcn_global_load_lds(
            (const __attribute__((address_space(1))) void*)(s + i * 2048),
            (__attribute__((address_space(3))) void*)(d + i * 2048), 16, 0, 0);
}

__global__ __launch_bounds__(128, 2)
void moe_kernel(const float* __restrict__ z, const float* __restrict__ probs,
                const float* __restrict__ b1, const float* __restrict__ b2,
                const float* __restrict__ W3, const float* __restrict__ b3,
                const uint16_t* __restrict__ w1b, const uint16_t* __restrict__ w2b,
                float* __restrict__ out) {
    __shared__ __align__(16) uint16_t wbuf[2][8192];      // 2 x 16 KB ping-pong
    __shared__ __align__(16) float preds_lds[BM * KEXP];  // 2 KB

    const int tid  = threadIdx.x;
    const int wave = tid >> 6;
    const int lane = tid & 63;
    const int r31  = lane & 31;    // A row (h/g2) and C/D col (batch row m)
    const int lh   = lane >> 5;    // lane half
    const int wg   = blockIdx.x;
    const long rowbase = (long)wg * BM;

    // z fragments: lane holds z[m = wave*32 + r31][d = 16t + 8*lh + j], t = 0..15
    bf16x8 zf[16];
    {
        const float* zr = z + (rowbase + wave * 32 + r31) * DD + lh * 8;
        #pragma unroll
        for (int t = 0; t < 16; ++t) {
            float4 x0 = *(const float4*)(zr + t * 16);
            float4 x1 = *(const float4*)(zr + t * 16 + 4);
            bf16x8 f;
            f[0] = f2bf(x0.x); f[1] = f2bf(x0.y); f[2] = f2bf(x0.z); f[3] = f2bf(x0.w);
            f[4] = f2bf(x1.x); f[5] = f2bf(x1.y); f[6] = f2bf(x1.z); f[7] = f2bf(x1.w);
            zf[t] = f;
        }
    }

    // prologue: stage expert 0, W1 quarter 0
    stage16k(w1b, wbuf[0], wave, lane);
    __syncthreads();

    int cur = 0;
    const int swz = lane & 7;      // XOR key: (row&7) for both W1 and W2 reads

    for (int ke = 0; ke < KEXP; ++ke) {
        bf16x8 pa[8];
        const uint16_t* w1e = w1b + ke * (HH * DD);
        const uint16_t* w2e = w2b + ke * (HH * HH);
        const float* bb1 = b1 + ke * HH;

        // ---- phases 0-3: layer-1 quarter q (32 h-rows, 16KB); stage next ----
        #pragma unroll
        for (int q = 0; q < 4; ++q) {
            if (q < 3) stage16k(w1e + (q + 1) * 8192, wbuf[cur ^ 1], wave, lane);
            else       stage16k(w2e,                  wbuf[cur ^ 1], wave, lane);

            // bias init: acc[reg] = b1[32q + (reg&3) + 8*(reg>>2) + 4*lh]
            f32x16 acc;
            {
                const float* bq = bb1 + 32 * q + 4 * lh;
                #pragma unroll
                for (int qd = 0; qd < 4; ++qd) {
                    f32x4 bv = *(const f32x4*)(bq + 8 * qd);
                    acc[4 * qd + 0] = bv[0]; acc[4 * qd + 1] = bv[1];
                    acc[4 * qd + 2] = bv[2]; acc[4 * qd + 3] = bv[3];
                }
            }
            const uint16_t* wrow = wbuf[cur] + r31 * 256;
            #pragma unroll
            for (int t = 0; t < 16; ++t) {
                int slot = (2 * t + lh) ^ swz;
                bf16x8 af = *(const bf16x8*)(wrow + slot * 8);
                acc = __builtin_amdgcn_mfma_f32_32x32x16_bf16(af, zf[t], acc, 0, 0, 0);
            }
            pa[2 * q]     = gelu_pack8(acc[0], acc[1], acc[2], acc[3], acc[4], acc[5], acc[6], acc[7]);
            pa[2 * q + 1] = gelu_pack8(acc[8], acc[9], acc[10], acc[11], acc[12], acc[13], acc[14], acc[15]);
            __syncthreads(); cur ^= 1;
        }

        float part = 0.f;

        // ---- phase E: layer-2 g2 rows 0-63 (2 MFMA blocks); stage W2 half 1 ----
        {
            stage16k(w2e + 8192, wbuf[cur ^ 1], wave, lane);
            f32x16 c0, c1;
            {
                const float* bq = b2 + ke * HH + 4 * lh;
                #pragma unroll
                for (int qd = 0; qd < 4; ++qd) {
                    f32x4 v0 = *(const f32x4*)(bq + 8 * qd);
                    f32x4 v1 = *(const f32x4*)(bq + 32 + 8 * qd);
                    c0[4 * qd + 0] = v0[0]; c0[4 * qd + 1] = v0[1]; c0[4 * qd + 2] = v0[2]; c0[4 * qd + 3] = v0[3];
                    c1[4 * qd + 0] = v1[0]; c1[4 * qd + 1] = v1[1]; c1[4 * qd + 2] = v1[2]; c1[4 * qd + 3] = v1[3];
                }
            }
            const uint16_t* wr0 = wbuf[cur] + r31 * 128;
            const uint16_t* wr1 = wbuf[cur] + (32 + r31) * 128;
            #pragma unroll
            for (int t2 = 0; t2 < 8; ++t2) {
                int slot = (2 * t2 + lh) ^ swz;
                c0 = __builtin_amdgcn_mfma_f32_32x32x16_bf16(*(const bf16x8*)(wr0 + slot * 8), pa[t2], c0, 0, 0, 0);
                c1 = __builtin_amdgcn_mfma_f32_32x32x16_bf16(*(const bf16x8*)(wr1 + slot * 8), pa[t2], c1, 0, 0, 0);
            }
            const float* w3p = W3 + ke * HH + 4 * lh;
            #pragma unroll
            for (int qd = 0; qd < 4; ++qd) {
                f32x4 w0 = *(const f32x4*)(w3p + 8 * qd);
                f32x4 w1v = *(const f32x4*)(w3p + 32 + 8 * qd);
                part = fmaf(gelu_erf(c0[4 * qd + 0]), w0[0], part);
                part = fmaf(gelu_erf(c0[4 * qd + 1]), w0[1], part);
                part = fmaf(gelu_erf(c0[4 * qd + 2]), w0[2], part);
                part = fmaf(gelu_erf(c0[4 * qd + 3]), w0[3], part);
                part = fmaf(gelu_erf(c1[4 * qd + 0]), w1v[0], part);
                part = fmaf(gelu_erf(c1[4 * qd + 1]), w1v[1], part);
                part = fmaf(gelu_erf(c1[4 * qd + 2]), w1v[2], part);
                part = fmaf(gelu_erf(c1[4 * qd + 3]), w1v[3], part);
            }
            __syncthreads(); cur ^= 1;
        }

        // ---- phase F: layer-2 g2 rows 64-127; stage next expert's W1 q0; reduce ----
        {
            if (ke + 1 < KEXP) stage16k(w1b + (ke + 1) * (HH * DD), wbuf[cur ^ 1], wave, lane);
            f32x16 c0, c1;
            {
                const float* bq = b2 + ke * HH + 64 + 4 * lh;
                #pragma unroll
                for (int qd = 0; qd < 4; ++qd) {
                    f32x4 v0 = *(const f32x4*)(bq + 8 * qd);
                    f32x4 v1 = *(const f32x4*)(bq + 32 + 8 * qd);
                    c0[4 * qd + 0] = v0[0]; c0[4 * qd + 1] = v0[1]; c0[4 * qd + 2] = v0[2]; c0[4 * qd + 3] = v0[3];
                    c1[4 * qd + 0] = v1[0]; c1[4 * qd + 1] = v1[1]; c1[4 * qd + 2] = v1[2]; c1[4 * qd + 3] = v1[3];
                }
            }
            const uint16_t* wr0 = wbuf[cur] + r31 * 128;
            const uint16_t* wr1 = wbuf[cur] + (32 + r31) * 128;
            #pragma unroll
            for (int t2 = 0; t2 < 8; ++t2) {
                int slot = (2 * t2 + lh) ^ swz;
                c0 = __builtin_amdgcn_mfma_f32_32x32x16_bf16(*(const bf16x8*)(wr0 + slot * 8), pa[t2], c0, 0, 0, 0);
                c1 = __builtin_amdgcn_mfma_f32_32x32x16_bf16(*(const bf16x8*)(wr1 + slot * 8), pa[t2], c1, 0, 0, 0);
            }
            const float* w3p = W3 + ke * HH + 64 + 4 * lh;
            #pragma unroll
            for (int qd = 0; qd < 4; ++qd) {
                f32x4 w0 = *(const f32x4*)(w3p + 8 * qd);
                f32x4 w1v = *(const f32x4*)(w3p + 32 + 8 * qd);
                part = fmaf(gelu_erf(c0[4 * qd + 0]), w0[0], part);
                part = fmaf(gelu_erf(c0[4 * qd + 1]), w0[1], part);
                part = fmaf(gelu_erf(c0[4 * qd + 2]), w0[2], part);
                part = fmaf(gelu_erf(c0[4 * qd + 3]), w0[3], part);
                part = fmaf(gelu_erf(c1[4 * qd + 0]), w1v[0], part);
                part = fmaf(gelu_erf(c1[4 * qd + 1]), w1v[1], part);
                part = fmaf(gelu_erf(c1[4 * qd + 2]), w1v[2], part);
                part = fmaf(gelu_erf(c1[4 * qd + 3]), w1v[3], part);
            }
            part += __shfl_xor(part, 32);   // lanes l and l+32 share batch row m = l&31
            if (lane < 32)
                preds_lds[(wave * 32 + lane) * KEXP + ke] = part + b3[ke];
            __syncthreads(); cur ^= 1;
        }
    }

    // expert_preds: coalesced 512 f32 per WG (128 threads x float4)
    {
        float4 v = *(const float4*)(preds_lds + tid * 4);
        *(float4*)(out + B_ROWS + rowbase * KEXP + tid * 4) = v;
    }
    // blended: 64 f32 per WG (probs straight from global, coalesced)
    if (tid < BM) {
        const float* pr = probs + (rowbase + tid) * KEXP;
        float4 p0 = *(const float4*)(pr);
        float4 p1 = *(const float4*)(pr + 4);
        const float* pd = preds_lds + tid * KEXP;
        float s = 0.f;
        s = fmaf(p0.x, pd[0], s); s = fmaf(p0.y, pd[1], s);
        s = fmaf(p0.z, pd[2], s); s = fmaf(p0.w, pd[3], s);
        s = fmaf(p1.x, pd[4], s); s = fmaf(p1.y, pd[5], s);
        s = fmaf(p1.z, pd[6], s); s = fmaf(p1.w, pd[7], s);
        out[rowbase + tid] = s;
    }
}

extern "C" void kernel_launch(void* const* d_in, const int* in_sizes, int n_in,
                              void* d_out, int out_size, void* d_ws, size_t ws_size,
                              hipStream_t stream) {
    const float* z     = (const float*)d_in[0];
    const float* probs = (const float*)d_in[1];
    const float* W1    = (const float*)d_in[2];
    const float* b1    = (const float*)d_in[3];
    const float* W2    = (const float*)d_in[4];
    const float* b2    = (const float*)d_in[5];
    const float* W3    = (const float*)d_in[6];
    const float* b3    = (const float*)d_in[7];
    float* out = (float*)d_out;

    uint16_t* w1b = (uint16_t*)d_ws;                       // 8*128*256 bf16 = 512 KB
    uint16_t* w2b = w1b + (size_t)KEXP * HH * DD;          // 8*128*128 bf16 = 256 KB

    const int totalw = KEXP * HH * DD + KEXP * HH * HH;    // 393216
    convert_weights<<<(totalw + 255) / 256, 256, 0, stream>>>(W1, W2, w1b, w2b);
    moe_kernel<<<B_ROWS / BM, 128, 0, stream>>>(z, probs, b1, b2, W3, b3, w1b, w2b, out);
}

// Round 11
// 211.849 us; speedup vs baseline: 2.4738x; 1.1403x over previous
//
#include <hip/hip_runtime.h>
#include <hip/hip_bf16.h>
#include <stdint.h>

// Problem constants
#define B_ROWS 131072
#define DD 256
#define KEXP 8
#define HH 128
#define BM 64         // rows per workgroup (4 waves x 16 rows)
#define NW 4          // waves per workgroup

typedef float  f32x4  __attribute__((ext_vector_type(4)));
typedef short  bf16x8 __attribute__((ext_vector_type(8)));

// native bf16 cast -> compiler emits v_cvt_pk_bf16_f32 (RTNE), ~5 inst cheaper than bit-twiddling
__device__ __forceinline__ unsigned short f2bf(float f) {
    __bf16 h = (__bf16)f;
    return __builtin_bit_cast(unsigned short, h);
}

// GELU with erf via Abramowitz-Stegun 7.1.25 (3-term, |erf err| <= 2.5e-5; gelu err ~6e-5,
// far below the bf16 rounding already present in the h tensors)
__device__ __forceinline__ float gelu_erf(float x) {
    float s = x * 0.70710678118654752f;
    float a = fabsf(s);
    float t = __builtin_amdgcn_rcpf(fmaf(0.47047f, a, 1.0f));
    float p = fmaf(t, 0.7478556f, -0.0958798f);
    p = fmaf(t, p, 0.3480242f);
    float e = __expf(-a * a);
    float Q = p * t * e;                        // = 1 - erf(a)
    float sel = (s >= 0.f) ? (2.0f - Q) : Q;    // 1 + erf(s)
    return 0.5f * x * sel;
}

__device__ __forceinline__ bf16x8 gelu_pack(f32x4 lo, f32x4 hi) {
    bf16x8 r;
    r[0] = f2bf(gelu_erf(lo[0])); r[1] = f2bf(gelu_erf(lo[1]));
    r[2] = f2bf(gelu_erf(lo[2])); r[3] = f2bf(gelu_erf(lo[3]));
    r[4] = f2bf(gelu_erf(hi[0])); r[5] = f2bf(gelu_erf(hi[1]));
    r[6] = f2bf(gelu_erf(hi[2])); r[7] = f2bf(gelu_erf(hi[3]));
    return r;
}

// Preconvert (round-4/8 verified layout):
//   W1 -> bf16 [k][h-row][32 slots][8], slot sc holds d-chunk kc = sc ^ (h&7).
//   W2 -> bf16 [k][g-row][16 slots][8], slot sc holds h-chunk kc = sc ^ (gr&7),
//         k-axis permuted by pi: h_bit4 <- k_bit2, h_bit3 <- k_bit4, h_bit2 <- k_bit3
//         (3-cycle on bits {2,3,4}), so layer-1 C/D fragments (gelu'd, packed pairwise)
//         feed layer-2's B operand directly with no LDS round-trip.
__global__ void convert_weights(const float* __restrict__ W1, const float* __restrict__ W2,
                                uint16_t* __restrict__ w1o, uint16_t* __restrict__ w2o) {
    int idx = blockIdx.x * blockDim.x + threadIdx.x;
    const int total1 = KEXP * HH * DD;           // 262144
    if (idx < total1) {
        int k   = idx >> 15;
        int rem = idx & 32767;
        int h   = rem >> 8;
        int r2  = rem & 255;
        int sc  = r2 >> 3;                       // 0..31
        int j   = r2 & 7;
        int kc  = sc ^ (h & 7);
        int d   = kc * 8 + j;
        w1o[idx] = f2bf(W1[(k * DD + d) * HH + h]);
        return;
    }
    int idx2 = idx - total1;
    const int total2 = KEXP * HH * HH;           // 131072
    if (idx2 < total2) {
        int k   = idx2 >> 14;
        int rem = idx2 & 16383;
        int gr  = rem >> 7;
        int r2  = rem & 127;
        int sc  = r2 >> 3;                       // 0..15
        int j   = r2 & 7;
        int kk  = (sc ^ (gr & 7)) * 8 + j;       // logical k position
        int h   = (kk & ~0x1C) | ((kk & 4) << 2) | ((kk & 0x18) >> 1);  // pi (3-cycle 2->4->3->2)
        w2o[idx2] = f2bf(W2[(k * HH + h) * HH + gr]);
    }
}

// stage 16KB with 256 threads: 4 waves x 4 iters x (64 lanes x 16B).
// LDS dest is wave-uniform base + lane*16 (HW rule).
__device__ __forceinline__ void stage16k(const uint16_t* __restrict__ src, uint16_t* dst,
                                         int wave, int lane) {
    const char* s = (const char*)src + wave * 1024 + lane * 16;
    char* d = (char*)dst + wave * 1024;
    #pragma unroll
    for (int i = 0; i < 4; ++i)
        __builtin_amdgcn_global_load_lds(
            (const __attribute__((address_space(1))) void*)(s + i * 4096),
            (__attribute__((address_space(3))) void*)(d + i * 4096), 16, 0, 0);
}

__global__ __launch_bounds__(256, 4)
void moe_kernel(const float* __restrict__ z, const float* __restrict__ probs,
                const float* __restrict__ b1, const float* __restrict__ b2,
                const float* __restrict__ W3, const float* __restrict__ b3,
                const uint16_t* __restrict__ w1b, const uint16_t* __restrict__ w2b,
                float* __restrict__ out) {
    __shared__ __align__(16) uint16_t wbuf[2][8192];      // 2 x 16 KB ping-pong
    __shared__ __align__(16) float preds_lds[BM * KEXP];  // 2 KB

    const int tid  = threadIdx.x;
    const int wave = tid >> 6;
    const int lane = tid & 63;
    const int c    = lane & 15;
    const int g    = lane >> 4;
    const int wg   = blockIdx.x;
    const long rowbase = (long)wg * BM;

    // z fragments in registers: lane holds z[row = wave*16 + c][d = kk*32 + 8g + j]
    bf16x8 zf[8];
    {
        const float* zr = z + (rowbase + wave * 16 + c) * DD;
        #pragma unroll
        for (int kk = 0; kk < 8; ++kk) {
            const float* p = zr + kk * 32 + g * 8;
            float4 x0 = *(const float4*)(p);
            float4 x1 = *(const float4*)(p + 4);
            bf16x8 f;
            f[0] = f2bf(x0.x); f[1] = f2bf(x0.y); f[2] = f2bf(x0.z); f[3] = f2bf(x0.w);
            f[4] = f2bf(x1.x); f[5] = f2bf(x1.y); f[6] = f2bf(x1.z); f[7] = f2bf(x1.w);
            zf[kk] = f;
        }
    }

    // prologue: stage expert 0, W1 quarter 0
    stage16k(w1b, wbuf[0], wave, lane);
    __syncthreads();

    int cur = 0;
    const int cswz = c & 7;

    for (int ke = 0; ke < KEXP; ++ke) {
        bf16x8 pa[4];
        const uint16_t* w1e = w1b + ke * (HH * DD);
        const uint16_t* w2e = w2b + ke * (HH * HH);
        const float* bb1 = b1 + ke * HH;

        // ---- phases A-D: layer-1 quarter q (32 h-rows, 16KB); stage next buffer ----
        #pragma unroll
        for (int q = 0; q < 4; ++q) {
            // stage: q<3 -> W1 quarter q+1 ; q==3 -> W2 half 0
            if (q < 3) stage16k(w1e + (q + 1) * 8192, wbuf[cur ^ 1], wave, lane);
            else       stage16k(w2e,                  wbuf[cur ^ 1], wave, lane);

            f32x4 a0 = *(const f32x4*)(bb1 + 32 * q +  0 + 4 * g);
            f32x4 a1 = *(const f32x4*)(bb1 + 32 * q + 16 + 4 * g);
            const uint16_t* wb = wbuf[cur];
            #pragma unroll
            for (int kk = 0; kk < 8; ++kk) {
                int slot = (4 * kk + g) ^ cswz;
                const uint16_t* base = wb + c * 256 + slot * 8;
                a0 = __builtin_amdgcn_mfma_f32_16x16x32_bf16(*(const bf16x8*)(base       ), zf[kk], a0, 0, 0, 0);
                a1 = __builtin_amdgcn_mfma_f32_16x16x32_bf16(*(const bf16x8*)(base + 4096), zf[kk], a1, 0, 0, 0);
            }
            pa[q] = gelu_pack(a0, a1);   // h rows 32q..32q+31 (pi-packed)
            __syncthreads(); cur ^= 1;
        }

        // ---- phase E: layer-2 half 0 (g2 rows 0-63); stage W2 half 1 ----
        f32x4 q0, q1, q2, q3;
        {
            stage16k(w2e + 8192, wbuf[cur ^ 1], wave, lane);
            const float* bb2 = b2 + ke * HH;
            q0 = *(const f32x4*)(bb2 +  0 + 4 * g);
            q1 = *(const f32x4*)(bb2 + 16 + 4 * g);
            q2 = *(const f32x4*)(bb2 + 32 + 4 * g);
            q3 = *(const f32x4*)(bb2 + 48 + 4 * g);
            const uint16_t* wb = wbuf[cur];
            #pragma unroll
            for (int kk2 = 0; kk2 < 4; ++kk2) {
                int slot = (4 * kk2 + g) ^ cswz;
                const uint16_t* base = wb + c * 128 + slot * 8;
                q0 = __builtin_amdgcn_mfma_f32_16x16x32_bf16(*(const bf16x8*)(base       ), pa[kk2], q0, 0, 0, 0);
                q1 = __builtin_amdgcn_mfma_f32_16x16x32_bf16(*(const bf16x8*)(base + 2048), pa[kk2], q1, 0, 0, 0);
                q2 = __builtin_amdgcn_mfma_f32_16x16x32_bf16(*(const bf16x8*)(base + 4096), pa[kk2], q2, 0, 0, 0);
                q3 = __builtin_amdgcn_mfma_f32_16x16x32_bf16(*(const bf16x8*)(base + 6144), pa[kk2], q3, 0, 0, 0);
            }
            __syncthreads(); cur ^= 1;
        }

        // ---- phase F: layer-2 half 1 (g2 rows 64-127); stage next expert's Q0; dot ----
        {
            if (ke + 1 < KEXP) stage16k(w1b + (ke + 1) * (HH * DD), wbuf[cur ^ 1], wave, lane);
            const float* bb2 = b2 + ke * HH + 64;
            f32x4 q4 = *(const f32x4*)(bb2 +  0 + 4 * g);
            f32x4 q5 = *(const f32x4*)(bb2 + 16 + 4 * g);
            f32x4 q6 = *(const f32x4*)(bb2 + 32 + 4 * g);
            f32x4 q7 = *(const f32x4*)(bb2 + 48 + 4 * g);
            const uint16_t* wb = wbuf[cur];
            #pragma unroll
            for (int kk2 = 0; kk2 < 4; ++kk2) {
                int slot = (4 * kk2 + g) ^ cswz;
                const uint16_t* base = wb + c * 128 + slot * 8;
                q4 = __builtin_amdgcn_mfma_f32_16x16x32_bf16(*(const bf16x8*)(base       ), pa[kk2], q4, 0, 0, 0);
                q5 = __builtin_amdgcn_mfma_f32_16x16x32_bf16(*(const bf16x8*)(base + 2048), pa[kk2], q5, 0, 0, 0);
                q6 = __builtin_amdgcn_mfma_f32_16x16x32_bf16(*(const bf16x8*)(base + 4096), pa[kk2], q6, 0, 0, 0);
                q7 = __builtin_amdgcn_mfma_f32_16x16x32_bf16(*(const bf16x8*)(base + 6144), pa[kk2], q7, 0, 0, 0);
            }

            // GELU + layer-3 dot: lane holds g2 = 16*hb2 + 4g + r, m = c
            const float* w3p = W3 + ke * HH;
            float part = 0.f;
            f32x4 w3v;
            #define DOT(qq, off) \
                w3v = *(const f32x4*)(w3p + off + 4 * g); \
                part = fmaf(gelu_erf(qq[0]), w3v[0], part); \
                part = fmaf(gelu_erf(qq[1]), w3v[1], part); \
                part = fmaf(gelu_erf(qq[2]), w3v[2], part); \
                part = fmaf(gelu_erf(qq[3]), w3v[3], part);
            DOT(q0,   0) DOT(q1,  16) DOT(q2,  32) DOT(q3,  48)
            DOT(q4,  64) DOT(q5,  80) DOT(q6,  96) DOT(q7, 112)
            #undef DOT
            part += __shfl_xor(part, 16);
            part += __shfl_xor(part, 32);
            if (g == 0)
                preds_lds[(wave * 16 + c) * KEXP + ke] = part + b3[ke];
            __syncthreads(); cur ^= 1;
        }
    }

    // expert_preds: coalesced 512 f32 per WG
    {
        float2 v = *(const float2*)(preds_lds + tid * 2);
        *(float2*)(out + B_ROWS + rowbase * KEXP + tid * 2) = v;
    }
    // blended: 64 f32 per WG (probs straight from global, coalesced)
    if (tid < BM) {
        const float* pr = probs + (rowbase + tid) * KEXP;
        float4 p0 = *(const float4*)(pr);
        float4 p1 = *(const float4*)(pr + 4);
        const float* pd = preds_lds + tid * KEXP;
        float s = 0.f;
        s = fmaf(p0.x, pd[0], s); s = fmaf(p0.y, pd[1], s);
        s = fmaf(p0.z, pd[2], s); s = fmaf(p0.w, pd[3], s);
        s = fmaf(p1.x, pd[4], s); s = fmaf(p1.y, pd[5], s);
        s = fmaf(p1.z, pd[6], s); s = fmaf(p1.w, pd[7], s);
        out[rowbase + tid] = s;
    }
}

extern "C" void kernel_launch(void* const* d_in, const int* in_sizes, int n_in,
                              void* d_out, int out_size, void* d_ws, size_t ws_size,
                              hipStream_t stream) {
    const float* z     = (const float*)d_in[0];
    const float* probs = (const float*)d_in[1];
    const float* W1    = (const float*)d_in[2];
    const float* b1    = (const float*)d_in[3];
    const float* W2    = (const float*)d_in[4];
    const float* b2    = (const float*)d_in[5];
    const float* W3    = (const float*)d_in[6];
    const float* b3    = (const float*)d_in[7];
    float* out = (float*)d_out;

    uint16_t* w1b = (uint16_t*)d_ws;                       // 8*128*256 bf16 = 512 KB
    uint16_t* w2b = w1b + (size_t)KEXP * HH * DD;          // 8*128*128 bf16 = 256 KB

    const int totalw = KEXP * HH * DD + KEXP * HH * HH;    // 393216
    convert_weights<<<(totalw + 255) / 256, 256, 0, stream>>>(W1, W2, w1b, w2b);
    moe_kernel<<<B_ROWS / BM, 256, 0, stream>>>(z, probs, b1, b2, W3, b3, w1b, w2b, out);
}

// Round 12
// 208.001 us; speedup vs baseline: 2.5196x; 1.0185x over previous
//
#include <hip/hip_runtime.h>
#include <hip/hip_bf16.h>
#include <stdint.h>

// Problem constants
#define B_ROWS 131072
#define DD 256
#define KEXP 8
#define HH 128
#define BM 64         // rows per workgroup (4 waves x 16 rows)
#define NW 4          // waves per workgroup

typedef float  f32x4  __attribute__((ext_vector_type(4)));
typedef short  bf16x8 __attribute__((ext_vector_type(8)));

// native bf16 cast -> v_cvt_pk_bf16_f32 (RTNE)
__device__ __forceinline__ unsigned short f2bf(float f) {
    __bf16 h = (__bf16)f;
    return __builtin_bit_cast(unsigned short, h);
}

// GELU with erf via Abramowitz-Stegun 7.1.25 (3-term, |erf err| <= 2.5e-5)
__device__ __forceinline__ float gelu_erf(float x) {
    float s = x * 0.70710678118654752f;
    float a = fabsf(s);
    float t = __builtin_amdgcn_rcpf(fmaf(0.47047f, a, 1.0f));
    float p = fmaf(t, 0.7478556f, -0.0958798f);
    p = fmaf(t, p, 0.3480242f);
    float e = __expf(-a * a);
    float Q = p * t * e;                        // = 1 - erf(a)
    float sel = (s >= 0.f) ? (2.0f - Q) : Q;    // 1 + erf(s)
    return 0.5f * x * sel;
}

__device__ __forceinline__ bf16x8 gelu_pack(f32x4 lo, f32x4 hi) {
    bf16x8 r;
    r[0] = f2bf(gelu_erf(lo[0])); r[1] = f2bf(gelu_erf(lo[1]));
    r[2] = f2bf(gelu_erf(lo[2])); r[3] = f2bf(gelu_erf(lo[3]));
    r[4] = f2bf(gelu_erf(hi[0])); r[5] = f2bf(gelu_erf(hi[1]));
    r[6] = f2bf(gelu_erf(hi[2])); r[7] = f2bf(gelu_erf(hi[3]));
    return r;
}

// Preconvert into MFMA-FRAGMENT-LINEAR order (zero-conflict LDS reads):
//   W1: [k:8][quarter q:4][frag = kk*2+hb:16][lane = g*16+c:64][j:8]
//       element = W1[(k*DD + d)*HH + h], d = kk*32 + g*8 + j, h = q*32 + hb*16 + c
//   W2: [k:8][half:2][frag = kk2*4+blk:16][lane = g*16+c:64][j:8]
//       logical k pos kl = kk2*32 + g*8 + j, source row pi(kl) (3-cycle on bits {2,3,4}:
//       h_bit4 <- k_bit2, h_bit3 <- k_bit4, h_bit2 <- k_bit3), g2 = half*64 + blk*16 + c
//       element = W2[(k*HH + pi(kl))*HH + g2]
//   A fragment read in-kernel: ds_read_b128 at (frag*1024 + lane*16) bytes -> 64 lanes
//   read one contiguous 1KB block: conflict-free, no per-read address math.
__global__ void convert_weights(const float* __restrict__ W1, const float* __restrict__ W2,
                                uint16_t* __restrict__ w1o, uint16_t* __restrict__ w2o) {
    int idx = blockIdx.x * blockDim.x + threadIdx.x;
    const int total1 = KEXP * HH * DD;           // 262144
    if (idx < total1) {
        int k    = idx >> 15;
        int rem  = idx & 32767;
        int q    = rem >> 13;
        int r2   = rem & 8191;
        int frag = r2 >> 9;
        int r3   = r2 & 511;
        int lane = r3 >> 3;
        int j    = r3 & 7;
        int kk   = frag >> 1;
        int hb   = frag & 1;
        int g    = lane >> 4;
        int c    = lane & 15;
        int d    = kk * 32 + g * 8 + j;
        int h    = q * 32 + hb * 16 + c;
        w1o[idx] = f2bf(W1[(k * DD + d) * HH + h]);
        return;
    }
    int idx2 = idx - total1;
    const int total2 = KEXP * HH * HH;           // 131072
    if (idx2 < total2) {
        int k    = idx2 >> 14;
        int rem  = idx2 & 16383;
        int half = rem >> 13;
        int r2   = rem & 8191;
        int frag = r2 >> 9;
        int r3   = r2 & 511;
        int lane = r3 >> 3;
        int j    = r3 & 7;
        int kk2  = frag >> 2;
        int blk  = frag & 3;
        int g    = lane >> 4;
        int c    = lane & 15;
        int kl   = kk2 * 32 + g * 8 + j;         // logical k position
        int h    = (kl & ~0x1C) | ((kl & 4) << 2) | ((kl & 0x18) >> 1);  // pi (3-cycle 2->4->3->2)
        int g2   = half * 64 + blk * 16 + c;
        w2o[idx2] = f2bf(W2[(k * HH + h) * HH + g2]);
    }
}

// stage 16KB with 256 threads: 4 waves x 4 iters x (64 lanes x 16B).
// LDS dest is wave-uniform base + lane*16 (HW rule); source is the linear image above.
__device__ __forceinline__ void stage16k(const uint16_t* __restrict__ src, uint16_t* dst,
                                         int wave, int lane) {
    const char* s = (const char*)src + wave * 1024 + lane * 16;
    char* d = (char*)dst + wave * 1024;
    #pragma unroll
    for (int i = 0; i < 4; ++i)
        __builtin_amdgcn_global_load_lds(
            (const __attribute__((address_space(1))) void*)(s + i * 4096),
            (__attribute__((address_space(3))) void*)(d + i * 4096), 16, 0, 0);
}

__global__ __launch_bounds__(256, 4)
void moe_kernel(const float* __restrict__ z, const float* __restrict__ probs,
                const float* __restrict__ b1, const float* __restrict__ b2,
                const float* __restrict__ W3, const float* __restrict__ b3,
                const uint16_t* __restrict__ w1b, const uint16_t* __restrict__ w2b,
                float* __restrict__ out) {
    __shared__ __align__(16) uint16_t wbuf[2][8192];      // 2 x 16 KB ping-pong
    __shared__ __align__(16) float preds_lds[BM * KEXP];  // 2 KB

    const int tid  = threadIdx.x;
    const int wave = tid >> 6;
    const int lane = tid & 63;
    const int c    = lane & 15;
    const int g    = lane >> 4;
    const int wg   = blockIdx.x;
    const long rowbase = (long)wg * BM;

    // z fragments in registers: lane holds z[row = wave*16 + c][d = kk*32 + 8g + j]
    bf16x8 zf[8];
    {
        const float* zr = z + (rowbase + wave * 16 + c) * DD;
        #pragma unroll
        for (int kk = 0; kk < 8; ++kk) {
            const float* p = zr + kk * 32 + g * 8;
            float4 x0 = *(const float4*)(p);
            float4 x1 = *(const float4*)(p + 4);
            bf16x8 f;
            f[0] = f2bf(x0.x); f[1] = f2bf(x0.y); f[2] = f2bf(x0.z); f[3] = f2bf(x0.w);
            f[4] = f2bf(x1.x); f[5] = f2bf(x1.y); f[6] = f2bf(x1.z); f[7] = f2bf(x1.w);
            zf[kk] = f;
        }
    }

    // prologue: stage expert 0, W1 quarter 0
    stage16k(w1b, wbuf[0], wave, lane);
    __syncthreads();

    int cur = 0;

    for (int ke = 0; ke < KEXP; ++ke) {
        bf16x8 pa[4];
        const uint16_t* w1e = w1b + ke * (HH * DD);
        const uint16_t* w2e = w2b + ke * (HH * HH);
        const float* bb1 = b1 + ke * HH;

        // ---- phases A-D: layer-1 quarter q (32 h-rows, 16KB); stage next buffer ----
        #pragma unroll
        for (int q = 0; q < 4; ++q) {
            // stage: q<3 -> W1 quarter q+1 ; q==3 -> W2 half 0
            if (q < 3) stage16k(w1e + (q + 1) * 8192, wbuf[cur ^ 1], wave, lane);
            else       stage16k(w2e,                  wbuf[cur ^ 1], wave, lane);

            f32x4 a0 = *(const f32x4*)(bb1 + 32 * q +  0 + 4 * g);
            f32x4 a1 = *(const f32x4*)(bb1 + 32 * q + 16 + 4 * g);
            const bf16x8* fb = (const bf16x8*)(wbuf[cur]) + lane;   // + frag*64 per fragment
            #pragma unroll
            for (int kk = 0; kk < 8; ++kk) {
                a0 = __builtin_amdgcn_mfma_f32_16x16x32_bf16(fb[kk * 128     ], zf[kk], a0, 0, 0, 0);
                a1 = __builtin_amdgcn_mfma_f32_16x16x32_bf16(fb[kk * 128 + 64], zf[kk], a1, 0, 0, 0);
            }
            pa[q] = gelu_pack(a0, a1);   // h rows 32q..32q+31 (pi-packed)
            __syncthreads(); cur ^= 1;
        }

        // ---- phase E: layer-2 half 0 (g2 rows 0-63); stage W2 half 1 ----
        f32x4 q0, q1, q2, q3;
        {
            stage16k(w2e + 8192, wbuf[cur ^ 1], wave, lane);
            const float* bb2 = b2 + ke * HH;
            q0 = *(const f32x4*)(bb2 +  0 + 4 * g);
            q1 = *(const f32x4*)(bb2 + 16 + 4 * g);
            q2 = *(const f32x4*)(bb2 + 32 + 4 * g);
            q3 = *(const f32x4*)(bb2 + 48 + 4 * g);
            const bf16x8* fb = (const bf16x8*)(wbuf[cur]) + lane;
            #pragma unroll
            for (int kk2 = 0; kk2 < 4; ++kk2) {
                q0 = __builtin_amdgcn_mfma_f32_16x16x32_bf16(fb[kk2 * 256      ], pa[kk2], q0, 0, 0, 0);
                q1 = __builtin_amdgcn_mfma_f32_16x16x32_bf16(fb[kk2 * 256 +  64], pa[kk2], q1, 0, 0, 0);
                q2 = __builtin_amdgcn_mfma_f32_16x16x32_bf16(fb[kk2 * 256 + 128], pa[kk2], q2, 0, 0, 0);
                q3 = __builtin_amdgcn_mfma_f32_16x16x32_bf16(fb[kk2 * 256 + 192], pa[kk2], q3, 0, 0, 0);
            }
            __syncthreads(); cur ^= 1;
        }

        // ---- phase F: layer-2 half 1 (g2 rows 64-127); stage next expert's Q0; dot ----
        {
            if (ke + 1 < KEXP) stage16k(w1b + (ke + 1) * (HH * DD), wbuf[cur ^ 1], wave, lane);
            const float* bb2 = b2 + ke * HH + 64;
            f32x4 q4 = *(const f32x4*)(bb2 +  0 + 4 * g);
            f32x4 q5 = *(const f32x4*)(bb2 + 16 + 4 * g);
            f32x4 q6 = *(const f32x4*)(bb2 + 32 + 4 * g);
            f32x4 q7 = *(const f32x4*)(bb2 + 48 + 4 * g);
            const bf16x8* fb = (const bf16x8*)(wbuf[cur]) + lane;
            #pragma unroll
            for (int kk2 = 0; kk2 < 4; ++kk2) {
                q4 = __builtin_amdgcn_mfma_f32_16x16x32_bf16(fb[kk2 * 256      ], pa[kk2], q4, 0, 0, 0);
                q5 = __builtin_amdgcn_mfma_f32_16x16x32_bf16(fb[kk2 * 256 +  64], pa[kk2], q5, 0, 0, 0);
                q6 = __builtin_amdgcn_mfma_f32_16x16x32_bf16(fb[kk2 * 256 + 128], pa[kk2], q6, 0, 0, 0);
                q7 = __builtin_amdgcn_mfma_f32_16x16x32_bf16(fb[kk2 * 256 + 192], pa[kk2], q7, 0, 0, 0);
            }

            // GELU + layer-3 dot: lane holds g2 = 16*hb2 + 4g + r, m = c
            const float* w3p = W3 + ke * HH;
            float part = 0.f;
            f32x4 w3v;
            #define DOT(qq, off) \
                w3v = *(const f32x4*)(w3p + off + 4 * g); \
                part = fmaf(gelu_erf(qq[0]), w3v[0], part); \
                part = fmaf(gelu_erf(qq[1]), w3v[1], part); \
                part = fmaf(gelu_erf(qq[2]), w3v[2], part); \
                part = fmaf(gelu_erf(qq[3]), w3v[3], part);
            DOT(q0,   0) DOT(q1,  16) DOT(q2,  32) DOT(q3,  48)
            DOT(q4,  64) DOT(q5,  80) DOT(q6,  96) DOT(q7, 112)
            #undef DOT
            part += __shfl_xor(part, 16);
            part += __shfl_xor(part, 32);
            if (g == 0)
                preds_lds[(wave * 16 + c) * KEXP + ke] = part + b3[ke];
            __syncthreads(); cur ^= 1;
        }
    }

    // expert_preds: coalesced 512 f32 per WG
    {
        float2 v = *(const float2*)(preds_lds + tid * 2);
        *(float2*)(out + B_ROWS + rowbase * KEXP + tid * 2) = v;
    }
    // blended: 64 f32 per WG (probs straight from global, coalesced)
    if (tid < BM) {
        const float* pr = probs + (rowbase + tid) * KEXP;
        float4 p0 = *(const float4*)(pr);
        float4 p1 = *(const float4*)(pr + 4);
        const float* pd = preds_lds + tid * KEXP;
        float s = 0.f;
        s = fmaf(p0.x, pd[0], s); s = fmaf(p0.y, pd[1], s);
        s = fmaf(p0.z, pd[2], s); s = fmaf(p0.w, pd[3], s);
        s = fmaf(p1.x, pd[4], s); s = fmaf(p1.y, pd[5], s);
        s = fmaf(p1.z, pd[6], s); s = fmaf(p1.w, pd[7], s);
        out[rowbase + tid] = s;
    }
}

extern "C" void kernel_launch(void* const* d_in, const int* in_sizes, int n_in,
                              void* d_out, int out_size, void* d_ws, size_t ws_size,
                              hipStream_t stream) {
    const float* z     = (const float*)d_in[0];
    const float* probs = (const float*)d_in[1];
    const float* W1    = (const float*)d_in[2];
    const float* b1    = (const float*)d_in[3];
    const float* W2    = (const float*)d_in[4];
    const float* b2    = (const float*)d_in[5];
    const float* W3    = (const float*)d_in[6];
    const float* b3    = (const float*)d_in[7];
    float* out = (float*)d_out;

    uint16_t* w1b = (uint16_t*)d_ws;                       // 8*128*256 bf16 = 512 KB
    uint16_t* w2b = w1b + (size_t)KEXP * HH * DD;          // 8*128*128 bf16 = 256 KB

    const int totalw = KEXP * HH * DD + KEXP * HH * HH;    // 393216
    convert_weights<<<(totalw + 255) / 256, 256, 0, stream>>>(W1, W2, w1b, w2b);
    moe_kernel<<<B_ROWS / BM, 256, 0, stream>>>(z, probs, b1, b2, W3, b3, w1b, w2b, out);
}